// Round 5
// baseline (394.211 us; speedup 1.0000x reference)
//
#include <hip/hip_runtime.h>
#include <hip/hip_bf16.h>

// y[b,f,c] = sum_hw x[b,c,hw] * k[f,c,hw];  out[b, f*C + c]
// B=256, F=16, C=256, HW=1024, fp32.
//
// History: R7 K-in-LDS barrier-free loop; R8 occupancy/XCD NEUTRAL; R9 RB=4
// NEUTRAL; R10 burst-reads REGRESSION (2.3 TB/s measured, serial phases);
// R11 coalesced store+transpose NEUTRAL (overhead recal: O~254us =>
// all R9-class kernels ~130-137us vs ~50us floor; stores/occupancy/RB/LDS
// all exonerated).
// R12 THEORY: x rows are 4KB-aligned blocks at (b*256+c)*4096. With 4KB
// HBM interleave over ~256 pseudo-channels, PC = (b*256+c) mod 256 = c
// (b*256 mod 256 == 0: b never changes the channel!). Every prior kernel
// binds block<->one c => block draws ALL its x bytes from ONE PC; per-PC
// demand at the 43us floor = ~24 GB/s = 100% of a PC -- the invariant
// ~2.3-3.5 TB/s ceiling. Fix: block owns TWO adjacent c's (K for both in
// 128KB LDS); even/odd 16-lane groups -> c0/c1, so every instant draws
// from 2 PCs. Same R9 compute loop. If neutral: theory dead -> roofline.

constexpr int Bb = 256;
constexpr int Ff = 16;
constexpr int Cc = 256;
constexpr int HW = 1024;
constexpr int CHW = Cc * HW;

constexpr int BT = 64;             // b per block (per c)
constexpr int RB = 4;              // b per thread
constexpr int NTHREADS = 512;      // 32 groups of 16: 16 b-groups x 2 c
constexpr int NJ = HW / 4 / 16;    // 16 j-iters (whole hw range)

__device__ __forceinline__ float dot4(float4 a, float4 b) {
    return a.x * b.x + a.y * b.y + a.z * b.z + a.w * b.w;
}
__device__ __forceinline__ float red16(float v) {
    v += __shfl_xor(v, 1);
    v += __shfl_xor(v, 2);
    v += __shfl_xor(v, 4);
    v += __shfl_xor(v, 8);
    return v;
}

template <bool TO_WS>
__global__ __launch_bounds__(NTHREADS)
void sle_kernel(const float* __restrict__ x, const float* __restrict__ k,
                float* __restrict__ dst) {   // TO_WS ? yT[c][b][f] : out[b][f*C+c]
    __shared__ float ldsK[2 * Ff * HW];       // 128 KiB: K for c0 and c1

    const int t   = threadIdx.x;
    const int thw = t & 15;                   // hw split within 16-lane group
    const int tbg = t >> 4;                   // 0..31
    const int csel = tbg & 1;                 // which c of the pair
    const int bg   = tbg >> 1;                // 0..15, b group

    // grid = 128 c-pairs x 4 b-tiles; same-pair blocks (g, g+128, ...) share
    // g%8 => same XCD => K-pair tile L2-resident for btiles 1..3.
    const int g     = blockIdx.x;
    const int cp    = g & 127;
    const int btile = g >> 7;                 // 0..3
    const int c0    = 2 * cp;                 // pair = (c0, c0+1): 2 distinct PCs
    const int b0    = btile * BT + bg * RB;

    // ---- stage K[f][.] for BOTH c's: 32768 floats, 16 float4/thread ----
    {
        const int r = t >> 4, lane16 = t & 15;    // 32 rows (2c x 16f)
        const int f = r & 15, cs = r >> 4;
        const float4* src = (const float4*)(k + (size_t)f * CHW
                                              + (size_t)(c0 + cs) * HW);
        float4* dstk = (float4*)(ldsK + (size_t)cs * (Ff * HW) + f * HW);
#pragma unroll
        for (int q = 0; q < 16; ++q)
            dstk[lane16 + 16 * q] = src[lane16 + 16 * q];
    }
    __syncthreads();

    const float* xb = x + (size_t)(c0 + csel) * HW;
    const int xo0 = (b0 + 0) * CHW;
    const int xo1 = (b0 + 1) * CHW;
    const int xo2 = (b0 + 2) * CHW;
    const int xo3 = (b0 + 3) * CHW;
    const float* kbase = ldsK + (size_t)csel * (Ff * HW);

    float4 a00={0,0,0,0}, a01={0,0,0,0}, a02={0,0,0,0}, a03={0,0,0,0};
    float4 a10={0,0,0,0}, a11={0,0,0,0}, a12={0,0,0,0}, a13={0,0,0,0};
    float4 a20={0,0,0,0}, a21={0,0,0,0}, a22={0,0,0,0}, a23={0,0,0,0};
    float4 a30={0,0,0,0}, a31={0,0,0,0}, a32={0,0,0,0}, a33={0,0,0,0};

    // ---- barrier-free main loop (R9 structure, kbase per-group) ----
#pragma unroll 2
    for (int j = 0; j < NJ; ++j) {
        const int off = 4 * (thw + 16 * j);
        const float4 xv0 = *(const float4*)(xb + xo0 + off);
        const float4 xv1 = *(const float4*)(xb + xo1 + off);
        const float4 xv2 = *(const float4*)(xb + xo2 + off);
        const float4 xv3 = *(const float4*)(xb + xo3 + off);

#define ACC_G(G, A0, A1, A2, A3) {                                      \
        const float* kp = kbase + (4 * (G)) * HW + off;                 \
        const float4 k0 = *(const float4*)(kp);                         \
        const float4 k1 = *(const float4*)(kp + HW);                    \
        const float4 k2 = *(const float4*)(kp + 2 * HW);                \
        const float4 k3 = *(const float4*)(kp + 3 * HW);                \
        A0.x += dot4(xv0, k0); A0.y += dot4(xv0, k1);                   \
        A0.z += dot4(xv0, k2); A0.w += dot4(xv0, k3);                   \
        A1.x += dot4(xv1, k0); A1.y += dot4(xv1, k1);                   \
        A1.z += dot4(xv1, k2); A1.w += dot4(xv1, k3);                   \
        A2.x += dot4(xv2, k0); A2.y += dot4(xv2, k1);                   \
        A2.z += dot4(xv2, k2); A2.w += dot4(xv2, k3);                   \
        A3.x += dot4(xv3, k0); A3.y += dot4(xv3, k1);                   \
        A3.z += dot4(xv3, k2); A3.w += dot4(xv3, k3); }

        ACC_G(0, a00, a10, a20, a30)
        ACC_G(1, a01, a11, a21, a31)
        ACC_G(2, a02, a12, a22, a32)
        ACC_G(3, a03, a13, a23, a33)
#undef ACC_G
    }

    // reduce the 16 hw-split lanes; all lanes valid (butterfly)
#define RED4(A) { A.x = red16(A.x); A.y = red16(A.y); \
                  A.z = red16(A.z); A.w = red16(A.w); }
    RED4(a00) RED4(a01) RED4(a02) RED4(a03)
    RED4(a10) RED4(a11) RED4(a12) RED4(a13)
    RED4(a20) RED4(a21) RED4(a22) RED4(a23)
    RED4(a30) RED4(a31) RED4(a32) RED4(a33)
#undef RED4

    __syncthreads();                          // done reading ldsK as K-tile
    // results: 2048 floats: [csel][local_b (0..63)][f]
    if (thw == 0) {
        const int base = csel * (BT * Ff) + (bg * RB) * Ff;
        float4* r0 = (float4*)(ldsK + base + 0 * Ff);
        float4* r1 = (float4*)(ldsK + base + 1 * Ff);
        float4* r2 = (float4*)(ldsK + base + 2 * Ff);
        float4* r3 = (float4*)(ldsK + base + 3 * Ff);
        r0[0] = a00; r0[1] = a01; r0[2] = a02; r0[3] = a03;
        r1[0] = a10; r1[1] = a11; r1[2] = a12; r1[3] = a13;
        r2[0] = a20; r2[1] = a21; r2[2] = a22; r2[3] = a23;
        r3[0] = a30; r3[1] = a31; r3[2] = a32; r3[3] = a33;
    }
    __syncthreads();

    if (TO_WS) {
        // one float4/thread, contiguous 4KB per (c, btile): yT[c][b][f]
        const int e  = 4 * t;                 // 0..2044
        const int cs = e >> 10;               // which c of pair
        const int rem = e & 1023;             // (local_b)*16 + f
        float4 v = *(const float4*)(ldsK + e);
        *(float4*)(dst + (size_t)(c0 + cs) * (Bb * Ff)
                       + (size_t)btile * (BT * Ff) + rem) = v;
    } else {
        // fallback: direct scattered stores (legacy path)
#pragma unroll
        for (int i = 0; i < (2 * BT * Ff) / NTHREADS; ++i) {   // 4
            const int idx = t + NTHREADS * i;  // csel*1024 + bl*16 + f
            const int cs  = idx >> 10;
            const int bl  = (idx >> 4) & 63;
            const int f   = idx & 15;
            dst[(size_t)(btile * BT + bl) * (Ff * Cc) + f * Cc + (c0 + cs)]
                = ldsK[idx];
        }
    }
}

// out[r][c] = yT[c][r], with r = b*16+f (R = 4096), c = channel (C = 256).
constexpr int TS = 64;
__global__ __launch_bounds__(256)
void trans_kernel(const float* __restrict__ yT, float* __restrict__ out) {
    __shared__ float tl[TS][TS + 1];
    const int t  = threadIdx.x;
    const int bi = blockIdx.x & 63;           // r-tile: 4096/64
    const int bj = blockIdx.x >> 6;           // c-tile: 256/64 -> 0..3
    const int r0 = bi * TS, c0 = bj * TS;
    const int rr = t & 15, cl = t >> 4;

#pragma unroll
    for (int q = 0; q < 4; ++q) {             // load: rows of yT (coalesced)
        const int c_local = cl + 16 * q;
        const float4 v = *(const float4*)(yT + (size_t)(c0 + c_local) * 4096
                                              + r0 + 4 * rr);
        tl[c_local][4 * rr + 0] = v.x;
        tl[c_local][4 * rr + 1] = v.y;
        tl[c_local][4 * rr + 2] = v.z;
        tl[c_local][4 * rr + 3] = v.w;
    }
    __syncthreads();
#pragma unroll
    for (int q = 0; q < 4; ++q) {             // store: rows of out (coalesced)
        const int r_local = cl + 16 * q;
        float4 v;
        v.x = tl[4 * rr + 0][r_local];
        v.y = tl[4 * rr + 1][r_local];
        v.z = tl[4 * rr + 2][r_local];
        v.w = tl[4 * rr + 3][r_local];
        *(float4*)(out + (size_t)(r0 + r_local) * 256 + c0 + 4 * rr) = v;
    }
}

extern "C" void kernel_launch(void* const* d_in, const int* in_sizes, int n_in,
                              void* d_out, int out_size, void* d_ws, size_t ws_size,
                              hipStream_t stream) {
    const float* x = (const float*)d_in[0];
    const float* k = (const float*)d_in[1];
    float* out = (float*)d_out;
    const int grid = (Cc / 2) * (Bb / BT);    // 128 pairs x 4 btiles = 512
    const size_t need = (size_t)Cc * Bb * Ff * sizeof(float);   // 4 MiB
    if (ws_size >= need && d_ws != nullptr) {
        float* yT = (float*)d_ws;
        sle_kernel<true><<<grid, NTHREADS, 0, stream>>>(x, k, yT);
        trans_kernel<<<256, 256, 0, stream>>>(yT, out);
    } else {
        sle_kernel<false><<<grid, NTHREADS, 0, stream>>>(x, k, out);
    }
}